// Round 4
// baseline (146.149 us; speedup 1.0000x reference)
//
#include <hip/hip_runtime.h>

// out[b,o] = p[b]*q[o] + bias[o]
//   p[b] = prod_i inputs[b,i]
//   q    = (1^T * prod_i C_i) @ projection
// K1: tree L1 (1024 cores -> 256 mats) fused with p-product pass
// K2: tree L2 (256 -> 16 mats)
// K3: chain 16 matvecs via shfl broadcast + projection -> q
// K4: out = p*q + bias (write-bound)
// (2nd resubmission: container-level infra failure both prior rounds; R0's
//  stub failed identically, so failures are uncorrelated with this source.)

// ---- 32x32 fp32 matmul, A,B,C in LDS, 256 threads, thread = (row j, col-quad kq)
__device__ __forceinline__ void mm32(const float* __restrict__ A,
                                     const float* __restrict__ B,
                                     float* __restrict__ C, int tid) {
    const int j = tid >> 3;      // 0..31 output row
    const int kq = tid & 7;      // 0..7  -> output cols 4kq..4kq+3
    float a[32];
    const float4* __restrict__ A4 = (const float4*)(A + j * 32);
#pragma unroll
    for (int t = 0; t < 8; ++t) {
        float4 v = A4[t];
        a[4 * t + 0] = v.x; a[4 * t + 1] = v.y;
        a[4 * t + 2] = v.z; a[4 * t + 3] = v.w;
    }
    const float4* __restrict__ B4 = (const float4*)B;
    float4 acc = make_float4(0.f, 0.f, 0.f, 0.f);
#pragma unroll
    for (int m = 0; m < 32; ++m) {
        float4 b = B4[m * 8 + kq];
        acc.x = fmaf(a[m], b.x, acc.x);
        acc.y = fmaf(a[m], b.y, acc.y);
        acc.z = fmaf(a[m], b.z, acc.z);
        acc.w = fmaf(a[m], b.w, acc.w);
    }
    ((float4*)(C + j * 32))[kq] = acc;
}

// ---- K1: 256 WGs. Tree level 1 (4-core product) + p-products for 16 rows.
__global__ __launch_bounds__(256) void k1(const float* __restrict__ cores,
                                          const float* __restrict__ inputs,
                                          float* __restrict__ l1,
                                          float* __restrict__ p) {
    __shared__ __align__(16) float c[4 * 1024];
    __shared__ __align__(16) float ping[1024];
    __shared__ __align__(16) float pong[1024];
    const int tid = threadIdx.x;
    const int s = blockIdx.x;
    const int lane = tid & 63;
    const int wid = tid >> 6;

    // issue core loads -> LDS
    const float4* src = (const float4*)(cores + (size_t)s * 4096);
    float4* cd = (float4*)c;
#pragma unroll
    for (int t = 0; t < 4; ++t) cd[tid + 256 * t] = src[tid + 256 * t];

    // issue p-pass input loads early (vmcnt overlap with the LDS tree below)
    float4 xr[16];
#pragma unroll
    for (int rr = 0; rr < 4; ++rr) {
        const int row = s * 16 + wid * 4 + rr;
        const float4* in4 = (const float4*)(inputs + (size_t)row * 1024);
#pragma unroll
        for (int t = 0; t < 4; ++t) xr[rr * 4 + t] = in4[lane + 64 * t];
    }

    __syncthreads();
    mm32(c, c + 1024, ping, tid);
    __syncthreads();
    mm32(ping, c + 2048, pong, tid);
    __syncthreads();
    mm32(pong, c + 3072, ping, tid);
    __syncthreads();
    ((float4*)(l1 + (size_t)s * 1024))[tid] = ((const float4*)ping)[tid];

    // p-products: one wave per row, 4 rows per wave
#pragma unroll
    for (int rr = 0; rr < 4; ++rr) {
        float4 x0 = xr[rr * 4 + 0], x1 = xr[rr * 4 + 1];
        float4 x2 = xr[rr * 4 + 2], x3 = xr[rr * 4 + 3];
        float pr = ((x0.x * x0.y) * (x0.z * x0.w)) * ((x1.x * x1.y) * (x1.z * x1.w)) *
                   ((x2.x * x2.y) * (x2.z * x2.w)) * ((x3.x * x3.y) * (x3.z * x3.w));
#pragma unroll
        for (int msk = 1; msk < 64; msk <<= 1) pr *= __shfl_xor(pr, msk);
        if (lane == 0) p[s * 16 + wid * 4 + rr] = pr;
    }
}

// ---- K2: 16 WGs, each multiplies 16 consecutive level-1 matrices (in order)
__global__ __launch_bounds__(256) void k2(const float* __restrict__ l1,
                                          float* __restrict__ l2) {
    __shared__ __align__(16) float m[16 * 1024];
    __shared__ __align__(16) float ping[1024];
    __shared__ __align__(16) float pong[1024];
    const int tid = threadIdx.x;
    const int s = blockIdx.x;
    const float4* src = (const float4*)(l1 + (size_t)s * 16384);
    float4* md = (float4*)m;
#pragma unroll
    for (int t = 0; t < 16; ++t) md[tid + 256 * t] = src[tid + 256 * t];
    __syncthreads();
    mm32(m, m + 1024, ping, tid);
    __syncthreads();
    float* A = ping;
    float* C = pong;
    for (int t = 2; t < 16; ++t) {
        mm32(A, m + t * 1024, C, tid);
        __syncthreads();
        float* tmp = A; A = C; C = tmp;
    }
    ((float4*)(l2 + (size_t)s * 1024))[tid] = ((const float4*)A)[tid];
}

// ---- K3: 1 WG. Wave 0 chains 16 matvecs (shfl broadcast), block projects q.
__global__ __launch_bounds__(256) void k3(const float* __restrict__ l2,
                                          const float* __restrict__ proj,
                                          float* __restrict__ q) {
    __shared__ __align__(16) float M[16 * 1024];
    __shared__ float w[32];
    const int tid = threadIdx.x;
    // stage the 16 matrices (64 KB) into LDS, coalesced
    const float4* src = (const float4*)l2;
    float4* Md = (float4*)M;
#pragma unroll
    for (int t = 0; t < 16; ++t) Md[tid + 256 * t] = src[tid + 256 * t];
    __syncthreads();

    if (tid < 64) {
        const int k = tid & 31;
        const int h = tid >> 5;     // half: j-range [h*16, h*16+16)
        float v[32];
#pragma unroll
        for (int j = 0; j < 32; ++j) v[j] = 1.0f;
        for (int sm = 0; sm < 16; ++sm) {
            const float* mat = M + sm * 1024;
            float acc = 0.f;
#pragma unroll
            for (int j = 0; j < 16; ++j) {
                const int jj = h * 16 + j;
                acc = fmaf(v[jj], mat[jj * 32 + k], acc);  // bank k: 2-way = free
            }
            acc += __shfl_down(acc, 32);                    // combine halves
#pragma unroll
            for (int j = 0; j < 32; ++j) v[j] = __shfl(acc, j);
        }
        if (tid < 32) w[k] = v[k];
    }
    __syncthreads();

    // q[o] = sum_j w[j] * proj[j,o] ; 128 threads x 1 float4 each
    if (tid < 128) {
        const float4* P4 = (const float4*)proj;
        float4 acc = make_float4(0.f, 0.f, 0.f, 0.f);
#pragma unroll
        for (int j = 0; j < 32; ++j) {
            float wj = w[j];
            float4 pv = P4[j * 128 + tid];
            acc.x = fmaf(wj, pv.x, acc.x);
            acc.y = fmaf(wj, pv.y, acc.y);
            acc.z = fmaf(wj, pv.z, acc.z);
            acc.w = fmaf(wj, pv.w, acc.w);
        }
        ((float4*)q)[tid] = acc;
    }
}

// ---- K4: write-bound epilogue. 512 WGs x 8 rows: out[b,:] = p[b]*q + bias.
__global__ __launch_bounds__(256) void k4(const float* __restrict__ p,
                                          const float* __restrict__ q,
                                          const float* __restrict__ bias,
                                          float* __restrict__ out) {
    __shared__ __align__(16) float qL[512];
    __shared__ __align__(16) float bL[512];
    __shared__ float pL[8];
    const int tid = threadIdx.x;
    const int s = blockIdx.x;
    if (tid < 128) {
        ((float4*)qL)[tid] = ((const float4*)q)[tid];
        ((float4*)bL)[tid] = ((const float4*)bias)[tid];
    }
    if (tid < 8) pL[tid] = p[s * 8 + tid];
    __syncthreads();
    const int row = s * 8 + (tid >> 5);
    const float pr = pL[tid >> 5];
    float4* o4 = (float4*)(out + (size_t)row * 512);
    const float4* q4 = (const float4*)qL;
    const float4* b4 = (const float4*)bL;
#pragma unroll
    for (int u = 0; u < 4; ++u) {
        const int c4 = u * 32 + (tid & 31);
        float4 qq = q4[c4];
        float4 bb = b4[c4];
        float4 r;
        r.x = fmaf(pr, qq.x, bb.x);
        r.y = fmaf(pr, qq.y, bb.y);
        r.z = fmaf(pr, qq.z, bb.z);
        r.w = fmaf(pr, qq.w, bb.w);
        o4[c4] = r;
    }
}

extern "C" void kernel_launch(void* const* d_in, const int* in_sizes, int n_in,
                              void* d_out, int out_size, void* d_ws, size_t ws_size,
                              hipStream_t stream) {
    const float* inputs = (const float*)d_in[0];   // [4096,1024]
    const float* cores  = (const float*)d_in[1];   // [1024,32,32]
    const float* proj   = (const float*)d_in[2];   // [32,512]
    const float* bias   = (const float*)d_in[3];   // [512]
    float* out = (float*)d_out;                    // [4096,512]
    float* w  = (float*)d_ws;
    float* l1 = w;                                   // 256*1024 floats
    float* l2 = w + 256 * 1024;                      // 16*1024 floats
    float* q  = w + 256 * 1024 + 16 * 1024;          // 512 floats
    float* p  = w + 256 * 1024 + 16 * 1024 + 512;    // 4096 floats

    k1<<<256, 256, 0, stream>>>(cores, inputs, l1, p);
    k2<<<16, 256, 0, stream>>>(l1, l2);
    k3<<<1, 256, 0, stream>>>(l2, proj, q);
    k4<<<512, 256, 0, stream>>>(p, q, bias, out);
}

// Round 6
// 94.263 us; speedup vs baseline: 1.5504x; 1.5504x over previous
//
#include <hip/hip_runtime.h>

// out[b,o] = p[b]*q[o] + bias[o]
//   p[b] = prod_i inputs[b,i];  q = (1^T * prod_i C_i) @ projection
// K1: tree L1 (1024 cores -> 256 mats) + p-product pass (consumed immediately)
// K2: tree L2 (256 -> 16 mats)
// K4: per-WG redundant 16-chain + projection (scalar-v, no reg arrays,
//     no single-WG kernel -- R4 showed 1-WG chain kernel = 61us latency trap),
//     then out = p*q + bias for 8 rows/WG.
// (Resubmission: R5 bench died on container infra; R4's counters motivated
//  this structure and no new evidence has arrived.)

// ---- 32x32 fp32 matmul, A,B,C in LDS, 256 threads, thread = (row j, col-quad kq)
__device__ __forceinline__ void mm32(const float* __restrict__ A,
                                     const float* __restrict__ B,
                                     float* __restrict__ C, int tid) {
    const int j = tid >> 3;      // 0..31 output row
    const int kq = tid & 7;      // 0..7  -> output cols 4kq..4kq+3
    float a[32];
    const float4* __restrict__ A4 = (const float4*)(A + j * 32);
#pragma unroll
    for (int t = 0; t < 8; ++t) {
        float4 v = A4[t];
        a[4 * t + 0] = v.x; a[4 * t + 1] = v.y;
        a[4 * t + 2] = v.z; a[4 * t + 3] = v.w;
    }
    const float4* __restrict__ B4 = (const float4*)B;
    float4 acc = make_float4(0.f, 0.f, 0.f, 0.f);
#pragma unroll
    for (int m = 0; m < 32; ++m) {
        float4 b = B4[m * 8 + kq];
        acc.x = fmaf(a[m], b.x, acc.x);
        acc.y = fmaf(a[m], b.y, acc.y);
        acc.z = fmaf(a[m], b.z, acc.z);
        acc.w = fmaf(a[m], b.w, acc.w);
    }
    ((float4*)(C + j * 32))[kq] = acc;
}

// ---- K1: 256 WGs. p-products for 16 rows (consumed immediately), then tree L1.
__global__ __launch_bounds__(256) void k1(const float* __restrict__ cores,
                                          const float* __restrict__ inputs,
                                          float* __restrict__ l1,
                                          float* __restrict__ p) {
    __shared__ __align__(16) float c[4 * 1024];
    __shared__ __align__(16) float ping[1024];
    __shared__ __align__(16) float pong[1024];
    const int tid = threadIdx.x;
    const int s = blockIdx.x;
    const int lane = tid & 63;
    const int wid = tid >> 6;

    // stage cores -> LDS (no long-lived registers)
    const float4* src = (const float4*)(cores + (size_t)s * 4096);
    float4* cd = (float4*)c;
#pragma unroll
    for (int t = 0; t < 4; ++t) cd[tid + 256 * t] = src[tid + 256 * t];

    // p-products: 4 rows per wave, each row's float4s consumed right away
    float prs[4];
#pragma unroll
    for (int rr = 0; rr < 4; ++rr) {
        const int row = s * 16 + wid * 4 + rr;
        const float4* in4 = (const float4*)(inputs + (size_t)row * 1024);
        float4 x0 = in4[lane];
        float4 x1 = in4[lane + 64];
        float4 x2 = in4[lane + 128];
        float4 x3 = in4[lane + 192];
        prs[rr] = ((x0.x * x0.y) * (x0.z * x0.w)) * ((x1.x * x1.y) * (x1.z * x1.w)) *
                  ((x2.x * x2.y) * (x2.z * x2.w)) * ((x3.x * x3.y) * (x3.z * x3.w));
    }
#pragma unroll
    for (int rr = 0; rr < 4; ++rr) {
        float pr = prs[rr];
#pragma unroll
        for (int msk = 1; msk < 64; msk <<= 1) pr *= __shfl_xor(pr, msk);
        if (lane == 0) p[s * 16 + wid * 4 + rr] = pr;
    }

    __syncthreads();
    mm32(c, c + 1024, ping, tid);
    __syncthreads();
    mm32(ping, c + 2048, pong, tid);
    __syncthreads();
    mm32(pong, c + 3072, ping, tid);
    __syncthreads();
    ((float4*)(l1 + (size_t)s * 1024))[tid] = ((const float4*)ping)[tid];
}

// ---- K2: 16 WGs, each multiplies 16 consecutive level-1 matrices (in order)
__global__ __launch_bounds__(256) void k2(const float* __restrict__ l1,
                                          float* __restrict__ l2) {
    __shared__ __align__(16) float m[16 * 1024];
    __shared__ __align__(16) float ping[1024];
    __shared__ __align__(16) float pong[1024];
    const int tid = threadIdx.x;
    const int s = blockIdx.x;
    const float4* src = (const float4*)(l1 + (size_t)s * 16384);
    float4* md = (float4*)m;
#pragma unroll
    for (int t = 0; t < 16; ++t) md[tid + 256 * t] = src[tid + 256 * t];
    __syncthreads();
    mm32(m, m + 1024, ping, tid);
    __syncthreads();
    float* A = ping;
    float* C = pong;
    for (int t = 2; t < 16; ++t) {
        mm32(A, m + t * 1024, C, tid);
        __syncthreads();
        float* tmp = A; A = C; C = tmp;
    }
    ((float4*)(l2 + (size_t)s * 1024))[tid] = ((const float4*)A)[tid];
}

// ---- K4: 512 WGs. Each: stage 16 mats, wave-0 scalar-v chain, project q,
//          then out[row,:] = p[row]*q + bias for 8 rows.
__global__ __launch_bounds__(256) void k4(const float* __restrict__ l2,
                                          const float* __restrict__ proj,
                                          const float* __restrict__ p,
                                          const float* __restrict__ bias,
                                          float* __restrict__ out) {
    __shared__ __align__(16) float M[16 * 1024];
    __shared__ __align__(16) float qL[512];
    __shared__ float w[32];
    const int tid = threadIdx.x;
    const int s = blockIdx.x;

    // stage the 16 chain matrices (64 KB), coalesced float4
    const float4* src = (const float4*)l2;
    float4* Md = (float4*)M;
#pragma unroll
    for (int t = 0; t < 16; ++t) Md[tid + 256 * t] = src[tid + 256 * t];
    __syncthreads();

    // wave 0: chain w^T = 1^T M0..M15. One scalar v per lane (lane k holds v[k],
    // lanes 32-63 duplicate harmlessly). LDS read mat[32j+k]: lane k -> bank k,
    // conflict-free. __shfl(v,j) = readlane broadcast, no register arrays.
    if (tid < 64) {
        const int k = tid & 31;
        float v = 1.0f;
        for (int sm = 0; sm < 16; ++sm) {
            const float* mat = M + sm * 1024 + k;
            float acc = 0.f;
#pragma unroll
            for (int j = 0; j < 32; ++j)
                acc = fmaf(__shfl(v, j), mat[32 * j], acc);
            v = acc;
        }
        if (tid < 32) w[k] = v;
    }
    __syncthreads();

    // projection: qL[o] = sum_j w[j]*proj[j,o]; 128 threads x 1 float4
    if (tid < 128) {
        const float4* P4 = (const float4*)proj;
        float4 acc = make_float4(0.f, 0.f, 0.f, 0.f);
#pragma unroll
        for (int j = 0; j < 32; ++j) {
            float wj = w[j];
            float4 pv = P4[j * 128 + tid];
            acc.x = fmaf(wj, pv.x, acc.x);
            acc.y = fmaf(wj, pv.y, acc.y);
            acc.z = fmaf(wj, pv.z, acc.z);
            acc.w = fmaf(wj, pv.w, acc.w);
        }
        ((float4*)qL)[tid] = acc;
    }
    __syncthreads();

    // epilogue: 8 rows/WG, 32 threads per row, 4 float4 per thread
    const int row = s * 8 + (tid >> 5);
    const float pr = p[row];
    const float4* q4 = (const float4*)qL;
    const float4* b4 = (const float4*)bias;
    float4* o4 = (float4*)(out + (size_t)row * 512);
#pragma unroll
    for (int u = 0; u < 4; ++u) {
        const int c4 = u * 32 + (tid & 31);
        float4 qq = q4[c4];
        float4 bb = b4[c4];
        float4 r;
        r.x = fmaf(pr, qq.x, bb.x);
        r.y = fmaf(pr, qq.y, bb.y);
        r.z = fmaf(pr, qq.z, bb.z);
        r.w = fmaf(pr, qq.w, bb.w);
        o4[c4] = r;
    }
}

extern "C" void kernel_launch(void* const* d_in, const int* in_sizes, int n_in,
                              void* d_out, int out_size, void* d_ws, size_t ws_size,
                              hipStream_t stream) {
    const float* inputs = (const float*)d_in[0];   // [4096,1024]
    const float* cores  = (const float*)d_in[1];   // [1024,32,32]
    const float* proj   = (const float*)d_in[2];   // [32,512]
    const float* bias   = (const float*)d_in[3];   // [512]
    float* out = (float*)d_out;                    // [4096,512]
    float* w  = (float*)d_ws;
    float* l1 = w;                                   // 256*1024 floats
    float* l2 = w + 256 * 1024;                      // 16*1024 floats
    float* p  = w + 256 * 1024 + 16 * 1024;          // 4096 floats

    k1<<<256, 256, 0, stream>>>(cores, inputs, l1, p);
    k2<<<16, 256, 0, stream>>>(l1, l2);
    k4<<<512, 256, 0, stream>>>(l2, proj, p, bias, out);
}

// Round 7
// 93.267 us; speedup vs baseline: 1.5670x; 1.0107x over previous
//
#include <hip/hip_runtime.h>

// out[b,o] = p[b]*q[o] + bias[o]
//   p[b] = prod_i inputs[b,i];  q = (1^T * prod_i C_i) @ projection
// K1: tree L1 (1024 cores -> 256 mats) + p-product pass
// K2: tree L2 (256 -> 16 mats)
// K4: 256 WGs: stage 16 mats, ILP-split scalar-v chain (wave 0), project,
//     out = p*q + bias for 16 rows/WG.
// R6 post-mortem: fixed harness cost ~77us; controllable ~17us, k4fused the
// biggest piece. This round: halve k4 redundancy (256 WGs), 4-way ILP chain,
// ILP mm32. No tiny-grid kernels (R4: 1-WG kernel = 61us latency/DVFS trap).

// ---- 32x32 fp32 matmul, A,B,C in LDS, 256 threads, thread = (row j, col-quad kq)
__device__ __forceinline__ void mm32(const float* __restrict__ A,
                                     const float* __restrict__ B,
                                     float* __restrict__ C, int tid) {
    const int j = tid >> 3;      // 0..31 output row
    const int kq = tid & 7;      // 0..7  -> output cols 4kq..4kq+3
    float a[32];
    const float4* __restrict__ A4 = (const float4*)(A + j * 32);
#pragma unroll
    for (int t = 0; t < 8; ++t) {
        float4 v = A4[t];
        a[4 * t + 0] = v.x; a[4 * t + 1] = v.y;
        a[4 * t + 2] = v.z; a[4 * t + 3] = v.w;
    }
    const float4* __restrict__ B4 = (const float4*)B;
    float4 acc0 = make_float4(0.f, 0.f, 0.f, 0.f);
    float4 acc1 = make_float4(0.f, 0.f, 0.f, 0.f);
#pragma unroll
    for (int m = 0; m < 16; ++m) {
        float4 b0 = B4[m * 8 + kq];
        float4 b1 = B4[(m + 16) * 8 + kq];
        acc0.x = fmaf(a[m], b0.x, acc0.x);
        acc0.y = fmaf(a[m], b0.y, acc0.y);
        acc0.z = fmaf(a[m], b0.z, acc0.z);
        acc0.w = fmaf(a[m], b0.w, acc0.w);
        acc1.x = fmaf(a[m + 16], b1.x, acc1.x);
        acc1.y = fmaf(a[m + 16], b1.y, acc1.y);
        acc1.z = fmaf(a[m + 16], b1.z, acc1.z);
        acc1.w = fmaf(a[m + 16], b1.w, acc1.w);
    }
    float4 acc;
    acc.x = acc0.x + acc1.x; acc.y = acc0.y + acc1.y;
    acc.z = acc0.z + acc1.z; acc.w = acc0.w + acc1.w;
    ((float4*)(C + j * 32))[kq] = acc;
}

// ---- K1: 256 WGs. p-products for 16 rows (consumed immediately), then tree L1.
__global__ __launch_bounds__(256) void k1(const float* __restrict__ cores,
                                          const float* __restrict__ inputs,
                                          float* __restrict__ l1,
                                          float* __restrict__ p) {
    __shared__ __align__(16) float c[4 * 1024];
    __shared__ __align__(16) float ping[1024];
    __shared__ __align__(16) float pong[1024];
    const int tid = threadIdx.x;
    const int s = blockIdx.x;
    const int lane = tid & 63;
    const int wid = tid >> 6;

    // stage cores -> LDS
    const float4* src = (const float4*)(cores + (size_t)s * 4096);
    float4* cd = (float4*)c;
#pragma unroll
    for (int t = 0; t < 4; ++t) cd[tid + 256 * t] = src[tid + 256 * t];

    // p-products: 4 rows per wave, each row's float4s consumed right away
    float prs[4];
#pragma unroll
    for (int rr = 0; rr < 4; ++rr) {
        const int row = s * 16 + wid * 4 + rr;
        const float4* in4 = (const float4*)(inputs + (size_t)row * 1024);
        float4 x0 = in4[lane];
        float4 x1 = in4[lane + 64];
        float4 x2 = in4[lane + 128];
        float4 x3 = in4[lane + 192];
        prs[rr] = ((x0.x * x0.y) * (x0.z * x0.w)) * ((x1.x * x1.y) * (x1.z * x1.w)) *
                  ((x2.x * x2.y) * (x2.z * x2.w)) * ((x3.x * x3.y) * (x3.z * x3.w));
    }
#pragma unroll
    for (int rr = 0; rr < 4; ++rr) {
        float pr = prs[rr];
#pragma unroll
        for (int msk = 1; msk < 64; msk <<= 1) pr *= __shfl_xor(pr, msk);
        if (lane == 0) p[s * 16 + wid * 4 + rr] = pr;
    }

    __syncthreads();
    mm32(c, c + 1024, ping, tid);
    __syncthreads();
    mm32(ping, c + 2048, pong, tid);
    __syncthreads();
    mm32(pong, c + 3072, ping, tid);
    __syncthreads();
    ((float4*)(l1 + (size_t)s * 1024))[tid] = ((const float4*)ping)[tid];
}

// ---- K2: 16 WGs, each multiplies 16 consecutive level-1 matrices (in order)
__global__ __launch_bounds__(256) void k2(const float* __restrict__ l1,
                                          float* __restrict__ l2) {
    __shared__ __align__(16) float m[16 * 1024];
    __shared__ __align__(16) float ping[1024];
    __shared__ __align__(16) float pong[1024];
    const int tid = threadIdx.x;
    const int s = blockIdx.x;
    const float4* src = (const float4*)(l1 + (size_t)s * 16384);
    float4* md = (float4*)m;
#pragma unroll
    for (int t = 0; t < 16; ++t) md[tid + 256 * t] = src[tid + 256 * t];
    __syncthreads();
    mm32(m, m + 1024, ping, tid);
    __syncthreads();
    float* A = ping;
    float* C = pong;
    for (int t = 2; t < 16; ++t) {
        mm32(A, m + t * 1024, C, tid);
        __syncthreads();
        float* tmp = A; A = C; C = tmp;
    }
    ((float4*)(l2 + (size_t)s * 1024))[tid] = ((const float4*)A)[tid];
}

// ---- K4: 256 WGs. Stage 16 mats + bias/p (overlapped), wave-0 ILP chain,
//          project q, then out[row,:] = p[row]*q + bias for 16 rows.
__global__ __launch_bounds__(256) void k4(const float* __restrict__ l2,
                                          const float* __restrict__ proj,
                                          const float* __restrict__ p,
                                          const float* __restrict__ bias,
                                          float* __restrict__ out) {
    __shared__ __align__(16) float M[16 * 1024];
    __shared__ __align__(16) float qL[512];
    __shared__ __align__(16) float bL[512];
    __shared__ float pL[16];
    __shared__ float w[32];
    const int tid = threadIdx.x;
    const int s = blockIdx.x;

    // stage the 16 chain matrices (64 KB), coalesced float4; bias+p overlap
    const float4* src = (const float4*)l2;
    float4* Md = (float4*)M;
#pragma unroll
    for (int t = 0; t < 16; ++t) Md[tid + 256 * t] = src[tid + 256 * t];
    if (tid < 128) ((float4*)bL)[tid] = ((const float4*)bias)[tid];
    if (tid < 16) pL[tid] = p[s * 16 + tid];
    __syncthreads();

    // wave 0: chain w^T = 1^T M0..M15. Lane k holds v[k] (lanes 32-63 dup).
    // 4 independent 8-fma chains per step (dep latency ~45cyc vs ~160 serial).
    // LDS mat[32j+k]: lane k -> bank k, conflict-free. __shfl = readlane.
    if (tid < 64) {
        const int k = tid & 31;
        float v = 1.0f;
        for (int sm = 0; sm < 16; ++sm) {
            const float* mat = M + sm * 1024 + k;
            float a0 = 0.f, a1 = 0.f, a2 = 0.f, a3 = 0.f;
#pragma unroll
            for (int j = 0; j < 8; ++j) {
                a0 = fmaf(__shfl(v, j),      mat[32 * j],        a0);
                a1 = fmaf(__shfl(v, j + 8),  mat[32 * (j + 8)],  a1);
                a2 = fmaf(__shfl(v, j + 16), mat[32 * (j + 16)], a2);
                a3 = fmaf(__shfl(v, j + 24), mat[32 * (j + 24)], a3);
            }
            v = (a0 + a1) + (a2 + a3);
        }
        if (tid < 32) w[k] = v;
    }
    __syncthreads();

    // projection: qL[o] = sum_j w[j]*proj[j,o]; 128 threads x 1 float4
    if (tid < 128) {
        const float4* P4 = (const float4*)proj;
        float4 acc = make_float4(0.f, 0.f, 0.f, 0.f);
#pragma unroll
        for (int j = 0; j < 32; ++j) {
            float wj = w[j];
            float4 pv = P4[j * 128 + tid];
            acc.x = fmaf(wj, pv.x, acc.x);
            acc.y = fmaf(wj, pv.y, acc.y);
            acc.z = fmaf(wj, pv.z, acc.z);
            acc.w = fmaf(wj, pv.w, acc.w);
        }
        ((float4*)qL)[tid] = acc;
    }
    __syncthreads();

    // epilogue: 16 rows/WG (two blocks of 8), 32 threads/row, 4 float4/thread
    const float4* q4 = (const float4*)qL;
    const float4* b4 = (const float4*)bL;
#pragma unroll
    for (int rb = 0; rb < 2; ++rb) {
        const int r8 = rb * 8 + (tid >> 5);
        const int row = s * 16 + r8;
        const float pr = pL[r8];
        float4* o4 = (float4*)(out + (size_t)row * 512);
#pragma unroll
        for (int u = 0; u < 4; ++u) {
            const int c4 = u * 32 + (tid & 31);
            float4 qq = q4[c4];
            float4 bb = b4[c4];
            float4 r;
            r.x = fmaf(pr, qq.x, bb.x);
            r.y = fmaf(pr, qq.y, bb.y);
            r.z = fmaf(pr, qq.z, bb.z);
            r.w = fmaf(pr, qq.w, bb.w);
            o4[c4] = r;
        }
    }
}

extern "C" void kernel_launch(void* const* d_in, const int* in_sizes, int n_in,
                              void* d_out, int out_size, void* d_ws, size_t ws_size,
                              hipStream_t stream) {
    const float* inputs = (const float*)d_in[0];   // [4096,1024]
    const float* cores  = (const float*)d_in[1];   // [1024,32,32]
    const float* proj   = (const float*)d_in[2];   // [32,512]
    const float* bias   = (const float*)d_in[3];   // [512]
    float* out = (float*)d_out;                    // [4096,512]
    float* w  = (float*)d_ws;
    float* l1 = w;                                   // 256*1024 floats
    float* l2 = w + 256 * 1024;                      // 16*1024 floats
    float* p  = w + 256 * 1024 + 16 * 1024;          // 4096 floats

    k1<<<256, 256, 0, stream>>>(cores, inputs, l1, p);
    k2<<<16, 256, 0, stream>>>(l1, l2);
    k4<<<256, 256, 0, stream>>>(l2, proj, p, bias, out);
}